// Round 4
// baseline (357.635 us; speedup 1.0000x reference)
//
#include <hip/hip_runtime.h>
#include <hip/hip_bf16.h>
#include <stdint.h>

// Causal self-attention, B=4, N=2048, D=1024.
// R3 (resubmit; prior round was a broker timeout, kernel never ran):
// all GEMMs -> 256x256 8-phase template (BK=64, 8 waves 2Mx4N, 512 thr,
// 128KiB dbuf LDS, counted vmcnt(4), XOR-swizzled LDS, setprio, XCD swizzle).

typedef __hip_bfloat16 bf16;
typedef short bf16x8v __attribute__((ext_vector_type(8)));
typedef short bf16x4v __attribute__((ext_vector_type(4)));
typedef float f32x4   __attribute__((ext_vector_type(4)));

#define DEV static __device__ __forceinline__

DEV void gload_lds16(const void* g, void* l) {
  __builtin_amdgcn_global_load_lds(
      (const __attribute__((address_space(1))) void*)g,
      (__attribute__((address_space(3))) void*)l, 16u, 0, 0u);
}

struct alignas(8) bf16q { bf16 a, b, c, d; };

// ---------------- f32 -> bf16 convert ----------------
__global__ __launch_bounds__(256)
void k_f32_to_bf16(const float* __restrict__ in, bf16* __restrict__ out, long n4) {
  long i = (long)blockIdx.x * blockDim.x + threadIdx.x;
  if (i >= n4) return;
  float4 v = ((const float4*)in)[i];
  bf16q o{__float2bfloat16(v.x), __float2bfloat16(v.y),
          __float2bfloat16(v.z), __float2bfloat16(v.w)};
  ((bf16q*)out)[i] = o;
}

// ---------------- 256^2 8-phase MFMA GEMM: C = A(MxK) @ B(NxK)^T [+bias] ----
// 8 waves as 2(M) x 4(N); per-wave 128x64 output = acc[8][4] of 16x16 frags.
// LDS: 2 bufs x { A: 2 halves 128x64, B: 2 halves 128x64 } bf16 = 128 KiB.
// Swizzle (both sides): byte ^= ((byte>>9)&3)<<5 within each 16 KiB half.
// Schedule per K-tile G (4 phases):
//   gate: vmcnt(4); barrier
//   ph0: ldA(mh0) ldB(nh0) | stage A1(G+1) | bar | mfma16 | bar
//   ph1: ldB(nh1)          | stage B1(G+1) | bar | mfma16 | bar
//   ph2: ldA(mh1)          | stage B0(G+2) | bar | mfma16 | bar
//   ph3:                     stage A0(G+2) | bar | mfma16 | bar
// CAUSAL: 0 none, 1 skip tiles above diagonal (S), 2 limit k (PV).
template<bool OUT_BF16, bool HAS_BIAS, int CAUSAL>
__global__ __launch_bounds__(512, 2)
void k_gemm8(const bf16* __restrict__ A, const bf16* __restrict__ B,
             const float* __restrict__ bias, void* __restrict__ Cout,
             int M, int N, int K, float scale,
             int lda, int ldb, int ldc, long sA, long sB, long sC)
{
  extern __shared__ char smem[];
  const int gx = gridDim.x;
  const int nwg = gx * gridDim.y;      // divisible by 8 by construction
  const int lin0 = blockIdx.y * gx + blockIdx.x;
  const int cpx = nwg >> 3;
  const int lin = (lin0 & 7) * cpx + (lin0 >> 3);   // XCD-aware swizzle
  const int tn = lin % gx, tm = lin / gx;
  const int bz = blockIdx.z;
  if (CAUSAL == 1 && tn > tm) return;

  const bf16* Ab = A + (long)bz * sA;
  const bf16* Bb = B + (long)bz * sB;
  const int m0 = tm * 256, n0 = tn * 256;

  int kend = K;
  if (CAUSAL == 2) { int ke = (tm + 1) * 256; kend = ke < K ? ke : K; }
  const int nt = kend >> 6;   // >= 4 always here

  const int t = threadIdx.x;
  const int lane = t & 63;
  const int w = t >> 6;
  const int wr = w >> 2, wc = w & 3;
  const int fr = lane & 15;
  const int kq = lane >> 4;          // 16B chunk index within 64-elem K row

  // stage one matrix-half (128 rows x 64 cols bf16 = 16 KiB) of K-tile tt.
  auto stage = [&](int isB, int h, int tt) {
    const bf16* src = isB ? Bb : Ab;
    const int ld = isB ? ldb : lda;
    const int b0_ = isB ? n0 : m0;
    char* dst = smem + (tt & 1) * 65536 + isB * 32768 + h * 16384;
    const int k0 = tt << 6;
#pragma unroll
    for (int j = 0; j < 2; ++j) {
      int lin16 = (t + j * 512) * 16;                    // linear LDS dest
      int lg = lin16 ^ (((lin16 >> 9) & 3) << 5);        // logical position
      int row = lg >> 7;                                 // 0..127
      int el = (lg & 127) >> 1;                          // 0..63 (mult of 8)
      gload_lds16(src + (long)(b0_ + h * 128 + row) * ld + (k0 + el),
                  dst + lin16);
    }
  };

  bf16x8v a[4][2], b0f[2][2], b1f[2][2];

  auto ldA = [&](int mh, int buf) {
    const char* base = smem + buf * 65536 + wr * 16384;
#pragma unroll
    for (int i = 0; i < 4; ++i)
#pragma unroll
      for (int ks = 0; ks < 2; ++ks) {
        int r = mh * 64 + i * 16 + fr;
        int lam = (r * 128 + ks * 64 + kq * 16) ^ (((r >> 2) & 3) << 5);
        a[i][ks] = *(const bf16x8v*)(base + lam);
      }
  };
  auto ldB = [&](bf16x8v (&bf_)[2][2], int nh, int buf) {
    const char* base = smem + buf * 65536 + 32768 + (wc >> 1) * 16384;
#pragma unroll
    for (int j = 0; j < 2; ++j)
#pragma unroll
      for (int ks = 0; ks < 2; ++ks) {
        int r = (wc & 1) * 64 + nh * 32 + j * 16 + fr;
        int lam = (r * 128 + ks * 64 + kq * 16) ^ (((r >> 2) & 3) << 5);
        bf_[j][ks] = *(const bf16x8v*)(base + lam);
      }
  };

  f32x4 acc[8][4] = {};

#define MFMA16(mh, bb, nh)                                                   \
  _Pragma("unroll") for (int i = 0; i < 4; ++i)                              \
  _Pragma("unroll") for (int j = 0; j < 2; ++j)                              \
  _Pragma("unroll") for (int ks = 0; ks < 2; ++ks)                           \
    acc[(mh)*4 + i][(nh)*2 + j] = __builtin_amdgcn_mfma_f32_16x16x32_bf16(   \
        a[i][ks], bb[j][ks], acc[(mh)*4 + i][(nh)*2 + j], 0, 0, 0);

  // prologue: mimic steady-state issue order (oldest first)
  stage(1, 0, 0); stage(0, 0, 0);   // "G-2 ph2/ph3" for G=0
  stage(0, 1, 0); stage(1, 1, 0);   // "G-1 ph0/ph1"
  stage(1, 0, 1); stage(0, 0, 1);   // "G-1 ph2/ph3"

  for (int G = 0; G < nt; ++G) {
    const int buf = G & 1;
    // K-tile gate: tile G's 4 halves landed; 2 halves (4 loads) stay in flight
    asm volatile("s_waitcnt vmcnt(4)" ::: "memory");
    __builtin_amdgcn_s_barrier();
    __builtin_amdgcn_sched_barrier(0);

    // ph0: quad (mh0, nh0)
    ldA(0, buf); ldB(b0f, 0, buf);
    if (G + 1 < nt) stage(0, 1, G + 1);
    __builtin_amdgcn_s_barrier();
    __builtin_amdgcn_sched_barrier(0);
    __builtin_amdgcn_s_setprio(1);
    MFMA16(0, b0f, 0);
    __builtin_amdgcn_s_setprio(0);
    __builtin_amdgcn_s_barrier();

    // ph1: quad (mh0, nh1)
    ldB(b1f, 1, buf);
    if (G + 1 < nt) stage(1, 1, G + 1);
    __builtin_amdgcn_s_barrier();
    __builtin_amdgcn_sched_barrier(0);
    __builtin_amdgcn_s_setprio(1);
    MFMA16(0, b1f, 1);
    __builtin_amdgcn_s_setprio(0);
    __builtin_amdgcn_s_barrier();

    // ph2: quad (mh1, nh0)
    ldA(1, buf);
    if (G + 2 < nt) stage(1, 0, G + 2);
    __builtin_amdgcn_s_barrier();
    __builtin_amdgcn_sched_barrier(0);
    __builtin_amdgcn_s_setprio(1);
    MFMA16(1, b0f, 0);
    __builtin_amdgcn_s_setprio(0);
    __builtin_amdgcn_s_barrier();

    // ph3: quad (mh1, nh1)
    if (G + 2 < nt) stage(0, 0, G + 2);
    __builtin_amdgcn_s_barrier();
    __builtin_amdgcn_sched_barrier(0);
    __builtin_amdgcn_s_setprio(1);
    MFMA16(1, b1f, 1);
    __builtin_amdgcn_s_setprio(0);
    __builtin_amdgcn_s_barrier();
  }
#undef MFMA16

  // epilogue: C/D layout col = lane&15, row = (lane>>4)*4 + reg
  const int rq = (lane >> 4) * 4;
#pragma unroll
  for (int nf = 0; nf < 4; ++nf) {
    const int n = n0 + wc * 64 + nf * 16 + fr;
    const float bv_ = HAS_BIAS ? bias[n] : 0.f;
#pragma unroll
    for (int mf = 0; mf < 8; ++mf) {
#pragma unroll
      for (int r = 0; r < 4; ++r) {
        const int m = m0 + wr * 128 + mf * 16 + rq + r;
        float v = acc[mf][nf][r] * scale + bv_;
        if (OUT_BF16)
          ((bf16*)Cout + (long)bz * sC)[(long)m * ldc + n] = __float2bfloat16(v);
        else
          ((float*)Cout + (long)bz * sC)[(long)m * ldc + n] = v;
      }
    }
  }
}

// ---------------- causal row softmax: S fp32 -> P bf16 (trimmed) ----------------
// zero-fills P up to 256-aligned kend (PV reads 256-wide k-tiles).
__global__ __launch_bounds__(256)
void k_softmax_causal(const float* __restrict__ S, bf16* __restrict__ P) {
  const long row = blockIdx.x;
  const int q = (int)(row & 2047);
  const int kend = ((q >> 8) + 1) << 8;   // multiple of 256
  const float* s = S + row * 2048;
  bf16* p = P + row * 2048;
  const int t = threadIdx.x;

  float e[8];
  float m = -3.4e38f;
#pragma unroll
  for (int i = 0; i < 8; i++) {
    int k = t + i * 256;
    float v = -3.4e38f;
    if (k <= q) v = s[k];
    e[i] = v;
    m = fmaxf(m, v);
  }
#pragma unroll
  for (int off = 1; off < 64; off <<= 1) m = fmaxf(m, __shfl_xor(m, off, 64));
  __shared__ float red[8];
  if ((t & 63) == 0) red[t >> 6] = m;
  __syncthreads();
  m = fmaxf(fmaxf(red[0], red[1]), fmaxf(red[2], red[3]));

  float sum = 0.f;
#pragma unroll
  for (int i = 0; i < 8; i++) {
    int k = t + i * 256;
    float x = (k <= q) ? __expf(e[i] - m) : 0.f;
    e[i] = x;
    sum += x;
  }
#pragma unroll
  for (int off = 1; off < 64; off <<= 1) sum += __shfl_xor(sum, off, 64);
  if ((t & 63) == 0) red[4 + (t >> 6)] = sum;
  __syncthreads();
  sum = red[4] + red[5] + red[6] + red[7];
  float inv = 1.f / sum;
#pragma unroll
  for (int i = 0; i < 8; i++) {
    int k = t + i * 256;
    if (k < kend) p[k] = __float2bfloat16(e[i] * inv);
  }
}

// ---------------- bf16 transpose with strides ----------------
__global__ __launch_bounds__(256)
void k_transpose_bf16(const bf16* __restrict__ V, bf16* __restrict__ Vt,
                      int in_ld, int out_ld, long in_bs, long out_bs) {
  __shared__ bf16 tile[64][68];
  const bf16* v = V + (long)blockIdx.z * in_bs;
  bf16* vt = Vt + (long)blockIdx.z * out_bs;
  const int k0 = blockIdx.y * 64;
  const int d0 = blockIdx.x * 64;
  const int t = threadIdx.x;
  const int c4 = (t & 15) * 4;
  const int r = t >> 4;
#pragma unroll
  for (int p2 = 0; p2 < 4; p2++) {
    int row = r + p2 * 16;
    bf16x4v val = *(const bf16x4v*)&v[(long)(k0 + row) * in_ld + d0 + c4];
    *(bf16x4v*)&tile[row][c4] = val;
  }
  __syncthreads();
#pragma unroll
  for (int p2 = 0; p2 < 4; p2++) {
    int drow = r + p2 * 16;
    bf16q o{tile[c4 + 0][drow], tile[c4 + 1][drow],
            tile[c4 + 2][drow], tile[c4 + 3][drow]};
    *(bf16q*)&vt[(long)(d0 + drow) * out_ld + k0 + c4] = o;
  }
}

// ---------------- launch ----------------
extern "C" void kernel_launch(void* const* d_in, const int* in_sizes, int n_in,
                              void* d_out, int out_size, void* d_ws, size_t ws_size,
                              hipStream_t stream)
{
  const float* X  = (const float*)d_in[0];
  const float* Wq = (const float*)d_in[1];
  const float* bq = (const float*)d_in[2];
  const float* Wk = (const float*)d_in[3];
  const float* bk = (const float*)d_in[4];
  const float* Wv = (const float*)d_in[5];
  const float* bv = (const float*)d_in[6];
  const float* Wo = (const float*)d_in[7];
  const float* bo = (const float*)d_in[8];

  const long Nt = 2048, D = 1024;
  const long TOK = 4 * Nt;  // 8192

  char* ws = (char*)d_ws;
  const size_t MB = 1024 * 1024;
  bf16*  QKVb = (bf16*)(ws + 0);          // 48 MiB  [8192][3072]
  bf16*  Wcat = (bf16*)(ws + 48 * MB);    //  6 MiB  [3072][1024]
  bf16*  Wob  = (bf16*)(ws + 54 * MB);    //  2 MiB
  float* bcat = (float*)(ws + 56 * MB);   //  12 KiB [3072]
  bf16*  Vt   = (bf16*)(ws + 57 * MB);    // 16 MiB  [4][1024][2048]
  bf16*  Cx   = (bf16*)(ws + 73 * MB);    // 16 MiB
  bf16*  Pb   = (bf16*)(ws + 89 * MB);    // 32 MiB
  bf16*  Xb   = (bf16*)(ws + 121 * MB);   // 16 MiB
  float* Sf   = (float*)(ws + 121 * MB);  // 64 MiB (overlaps Xb; Xb dead after QKV)

  const int SMEM = 131072;
  hipFuncSetAttribute((const void*)k_gemm8<true,  true,  0>,
                      hipFuncAttributeMaxDynamicSharedMemorySize, SMEM);
  hipFuncSetAttribute((const void*)k_gemm8<false, false, 1>,
                      hipFuncAttributeMaxDynamicSharedMemorySize, SMEM);
  hipFuncSetAttribute((const void*)k_gemm8<true,  false, 2>,
                      hipFuncAttributeMaxDynamicSharedMemorySize, SMEM);
  hipFuncSetAttribute((const void*)k_gemm8<false, true,  0>,
                      hipFuncAttributeMaxDynamicSharedMemorySize, SMEM);

  dim3 blk(256), blk8(512);

  // converts
  k_f32_to_bf16<<<dim3(8192), blk, 0, stream>>>(X,  Xb,  TOK * D / 4);
  k_f32_to_bf16<<<dim3(1024), blk, 0, stream>>>(Wq, Wcat,             D * D / 4);
  k_f32_to_bf16<<<dim3(1024), blk, 0, stream>>>(Wk, Wcat + D * D,     D * D / 4);
  k_f32_to_bf16<<<dim3(1024), blk, 0, stream>>>(Wv, Wcat + 2 * D * D, D * D / 4);
  k_f32_to_bf16<<<dim3(1024), blk, 0, stream>>>(Wo, Wob,              D * D / 4);

  hipMemcpyAsync(bcat,       bq, D * 4, hipMemcpyDeviceToDevice, stream);
  hipMemcpyAsync(bcat + D,   bk, D * 4, hipMemcpyDeviceToDevice, stream);
  hipMemcpyAsync(bcat + 2*D, bv, D * 4, hipMemcpyDeviceToDevice, stream);

  // fused QKV: [8192,3072] = Xb @ Wcat^T + bcat
  k_gemm8<true, true, 0><<<dim3(12, 32, 1), blk8, SMEM, stream>>>(
      Xb, Wcat, bcat, QKVb, 8192, 3072, 1024, 1.f,
      1024, 1024, 3072, 0, 0, 0);

  // V transpose per batch
  k_transpose_bf16<<<dim3(16, 32, 4), blk, 0, stream>>>(
      QKVb + 2048, Vt, 3072, 2048, Nt * 3072, D * Nt);

  // S = Q @ K^T / 32 (causal tile skip, fp32)
  k_gemm8<false, false, 1><<<dim3(8, 8, 4), blk8, SMEM, stream>>>(
      QKVb, QKVb + 1024, nullptr, Sf, 2048, 2048, 1024, 0.03125f,
      3072, 3072, 2048, Nt * 3072, Nt * 3072, Nt * Nt);

  // softmax -> P bf16
  k_softmax_causal<<<dim3(8192), blk, 0, stream>>>(Sf, Pb);

  // ctx = P @ Vt^T (k-limited)
  k_gemm8<true, false, 2><<<dim3(4, 8, 4), blk8, SMEM, stream>>>(
      Pb, Vt, nullptr, Cx, 2048, 1024, 2048, 1.f,
      2048, 2048, 1024, Nt * Nt, D * Nt, Nt * D);

  // out = ctx @ Wo^T + bo (fp32)
  k_gemm8<false, true, 0><<<dim3(4, 32, 1), blk8, SMEM, stream>>>(
      Cx, Wob, bo, d_out, 8192, 1024, 1024, 1.f,
      1024, 1024, 1024, 0, 0, 0);
}

// Round 5
// 340.908 us; speedup vs baseline: 1.0491x; 1.0491x over previous
//
#include <hip/hip_runtime.h>
#include <hip/hip_bf16.h>
#include <stdint.h>

// Causal self-attention, B=4, N=2048, D=1024.
// R5: fix LDS swizzle (3-bit slot XOR, (row&7)<<4 — uniform 8-lane/slot) and
// last-K-tile vmcnt(0) race. Structure otherwise identical to R4's 256^2
// 8-phase template (BK=64, 8 waves 2Mx4N, 512 thr, dbuf, counted vmcnt).

typedef __hip_bfloat16 bf16;
typedef short bf16x8v __attribute__((ext_vector_type(8)));
typedef short bf16x4v __attribute__((ext_vector_type(4)));
typedef float f32x4   __attribute__((ext_vector_type(4)));

#define DEV static __device__ __forceinline__

DEV void gload_lds16(const void* g, void* l) {
  __builtin_amdgcn_global_load_lds(
      (const __attribute__((address_space(1))) void*)g,
      (__attribute__((address_space(3))) void*)l, 16u, 0, 0u);
}

struct alignas(8) bf16q { bf16 a, b, c, d; };

// ---------------- f32 -> bf16 convert ----------------
__global__ __launch_bounds__(256)
void k_f32_to_bf16(const float* __restrict__ in, bf16* __restrict__ out, long n4) {
  long i = (long)blockIdx.x * blockDim.x + threadIdx.x;
  if (i >= n4) return;
  float4 v = ((const float4*)in)[i];
  bf16q o{__float2bfloat16(v.x), __float2bfloat16(v.y),
          __float2bfloat16(v.z), __float2bfloat16(v.w)};
  ((bf16q*)out)[i] = o;
}

// ---------------- 256^2 8-phase MFMA GEMM: C = A(MxK) @ B(NxK)^T [+bias] ----
// 8 waves as 2(M) x 4(N); per-wave 128x64 output = acc[8][4] of 16x16 frags.
// LDS: 2 bufs x { A: 2 halves 128x64, B: 2 halves 128x64 } bf16 = 128 KiB.
// Swizzle (both sides, involution on 16B chunks): off ^= ((off>>7)&7)<<4.
//   read slot = (4ks+kq) ^ (row&7): 8 lanes per 16B slot, uniform -> ~conflict-free.
// Schedule per K-tile G (4 phases):
//   gate: vmcnt(4) (last tile: vmcnt(0)); barrier
//   ph0: ldA(mh0) ldB(nh0) | stage A1(G+1) | bar | mfma16 | bar
//   ph1: ldB(nh1)          | stage B1(G+1) | bar | mfma16 | bar
//   ph2: ldA(mh1)          | stage B0(G+2) | bar | mfma16 | bar
//   ph3:                     stage A0(G+2) | bar | mfma16 | bar
// CAUSAL: 0 none, 1 skip tiles above diagonal (S), 2 limit k (PV).
template<bool OUT_BF16, bool HAS_BIAS, int CAUSAL>
__global__ __launch_bounds__(512, 2)
void k_gemm8(const bf16* __restrict__ A, const bf16* __restrict__ B,
             const float* __restrict__ bias, void* __restrict__ Cout,
             int M, int N, int K, float scale,
             int lda, int ldb, int ldc, long sA, long sB, long sC)
{
  extern __shared__ char smem[];
  const int gx = gridDim.x;
  const int nwg = gx * gridDim.y;      // divisible by 8 by construction
  const int lin0 = blockIdx.y * gx + blockIdx.x;
  const int cpx = nwg >> 3;
  const int lin = (lin0 & 7) * cpx + (lin0 >> 3);   // XCD-aware swizzle
  const int tn = lin % gx, tm = lin / gx;
  const int bz = blockIdx.z;
  if (CAUSAL == 1 && tn > tm) return;

  const bf16* Ab = A + (long)bz * sA;
  const bf16* Bb = B + (long)bz * sB;
  const int m0 = tm * 256, n0 = tn * 256;

  int kend = K;
  if (CAUSAL == 2) { int ke = (tm + 1) * 256; kend = ke < K ? ke : K; }
  const int nt = kend >> 6;   // >= 4 always here

  const int t = threadIdx.x;
  const int lane = t & 63;
  const int w = t >> 6;
  const int wr = w >> 2, wc = w & 3;
  const int fr = lane & 15;
  const int kq = lane >> 4;          // 16B chunk index within 64-elem K row

  // stage one matrix-half (128 rows x 64 cols bf16 = 16 KiB) of K-tile tt.
  auto stage = [&](int isB, int h, int tt) {
    const bf16* src = isB ? Bb : Ab;
    const int ld = isB ? ldb : lda;
    const int b0_ = isB ? n0 : m0;
    char* dst = smem + (tt & 1) * 65536 + isB * 32768 + h * 16384;
    const int k0 = tt << 6;
#pragma unroll
    for (int j = 0; j < 2; ++j) {
      int lin16 = (t + j * 512) * 16;                    // linear LDS dest
      int lg = lin16 ^ (((lin16 >> 7) & 7) << 4);        // logical position
      int row = lg >> 7;                                 // 0..127
      int el = (lg & 127) >> 1;                          // 0..63 (mult of 8)
      gload_lds16(src + (long)(b0_ + h * 128 + row) * ld + (k0 + el),
                  dst + lin16);
    }
  };

  bf16x8v a[4][2], b0f[2][2], b1f[2][2];

  auto ldA = [&](int mh, int buf) {
    const char* base = smem + buf * 65536 + wr * 16384;
#pragma unroll
    for (int i = 0; i < 4; ++i)
#pragma unroll
      for (int ks = 0; ks < 2; ++ks) {
        int r = mh * 64 + i * 16 + fr;
        int off = r * 128 + ks * 64 + kq * 16;
        int lam = off ^ (((off >> 7) & 7) << 4);
        a[i][ks] = *(const bf16x8v*)(base + lam);
      }
  };
  auto ldB = [&](bf16x8v (&bf_)[2][2], int nh, int buf) {
    const char* base = smem + buf * 65536 + 32768 + (wc >> 1) * 16384;
#pragma unroll
    for (int j = 0; j < 2; ++j)
#pragma unroll
      for (int ks = 0; ks < 2; ++ks) {
        int r = (wc & 1) * 64 + nh * 32 + j * 16 + fr;
        int off = r * 128 + ks * 64 + kq * 16;
        int lam = off ^ (((off >> 7) & 7) << 4);
        bf_[j][ks] = *(const bf16x8v*)(base + lam);
      }
  };

  f32x4 acc[8][4] = {};

#define MFMA16(mh, bb, nh)                                                   \
  _Pragma("unroll") for (int i = 0; i < 4; ++i)                              \
  _Pragma("unroll") for (int j = 0; j < 2; ++j)                              \
  _Pragma("unroll") for (int ks = 0; ks < 2; ++ks)                           \
    acc[(mh)*4 + i][(nh)*2 + j] = __builtin_amdgcn_mfma_f32_16x16x32_bf16(   \
        a[i][ks], bb[j][ks], acc[(mh)*4 + i][(nh)*2 + j], 0, 0, 0);

  // prologue: mimic steady-state issue order (oldest first)
  stage(1, 0, 0); stage(0, 0, 0);   // "G-2 ph2/ph3" for G=0
  stage(0, 1, 0); stage(1, 1, 0);   // "G-1 ph0/ph1"
  stage(1, 0, 1); stage(0, 0, 1);   // "G-1 ph2/ph3"

  for (int G = 0; G < nt; ++G) {
    const int buf = G & 1;
    // K-tile gate. Steady state: tile G's 8 loads drained, 4 of G+1 in flight.
    // Last tile: nothing behind it -> must drain fully (fixes latent race).
    if (G + 1 < nt) asm volatile("s_waitcnt vmcnt(4)" ::: "memory");
    else            asm volatile("s_waitcnt vmcnt(0)" ::: "memory");
    __builtin_amdgcn_s_barrier();
    __builtin_amdgcn_sched_barrier(0);

    // ph0: quad (mh0, nh0)
    ldA(0, buf); ldB(b0f, 0, buf);
    if (G + 1 < nt) stage(0, 1, G + 1);
    __builtin_amdgcn_s_barrier();
    __builtin_amdgcn_sched_barrier(0);
    __builtin_amdgcn_s_setprio(1);
    MFMA16(0, b0f, 0);
    __builtin_amdgcn_s_setprio(0);
    __builtin_amdgcn_s_barrier();

    // ph1: quad (mh0, nh1)
    ldB(b1f, 1, buf);
    if (G + 1 < nt) stage(1, 1, G + 1);
    __builtin_amdgcn_s_barrier();
    __builtin_amdgcn_sched_barrier(0);
    __builtin_amdgcn_s_setprio(1);
    MFMA16(0, b1f, 1);
    __builtin_amdgcn_s_setprio(0);
    __builtin_amdgcn_s_barrier();

    // ph2: quad (mh1, nh0)
    ldA(1, buf);
    if (G + 2 < nt) stage(1, 0, G + 2);
    __builtin_amdgcn_s_barrier();
    __builtin_amdgcn_sched_barrier(0);
    __builtin_amdgcn_s_setprio(1);
    MFMA16(1, b0f, 0);
    __builtin_amdgcn_s_setprio(0);
    __builtin_amdgcn_s_barrier();

    // ph3: quad (mh1, nh1)
    if (G + 2 < nt) stage(0, 0, G + 2);
    __builtin_amdgcn_s_barrier();
    __builtin_amdgcn_sched_barrier(0);
    __builtin_amdgcn_s_setprio(1);
    MFMA16(1, b1f, 1);
    __builtin_amdgcn_s_setprio(0);
    __builtin_amdgcn_s_barrier();
  }
#undef MFMA16

  // epilogue: C/D layout col = lane&15, row = (lane>>4)*4 + reg
  const int rq = (lane >> 4) * 4;
#pragma unroll
  for (int nf = 0; nf < 4; ++nf) {
    const int n = n0 + wc * 64 + nf * 16 + fr;
    const float bv_ = HAS_BIAS ? bias[n] : 0.f;
#pragma unroll
    for (int mf = 0; mf < 8; ++mf) {
#pragma unroll
      for (int r = 0; r < 4; ++r) {
        const int m = m0 + wr * 128 + mf * 16 + rq + r;
        float v = acc[mf][nf][r] * scale + bv_;
        if (OUT_BF16)
          ((bf16*)Cout + (long)bz * sC)[(long)m * ldc + n] = __float2bfloat16(v);
        else
          ((float*)Cout + (long)bz * sC)[(long)m * ldc + n] = v;
      }
    }
  }
}

// ---------------- causal row softmax: S fp32 -> P bf16 (trimmed) ----------------
// zero-fills P up to 256-aligned kend (PV reads 256-wide k-tiles).
__global__ __launch_bounds__(256)
void k_softmax_causal(const float* __restrict__ S, bf16* __restrict__ P) {
  const long row = blockIdx.x;
  const int q = (int)(row & 2047);
  const int kend = ((q >> 8) + 1) << 8;   // multiple of 256
  const float* s = S + row * 2048;
  bf16* p = P + row * 2048;
  const int t = threadIdx.x;

  float e[8];
  float m = -3.4e38f;
#pragma unroll
  for (int i = 0; i < 8; i++) {
    int k = t + i * 256;
    float v = -3.4e38f;
    if (k <= q) v = s[k];
    e[i] = v;
    m = fmaxf(m, v);
  }
#pragma unroll
  for (int off = 1; off < 64; off <<= 1) m = fmaxf(m, __shfl_xor(m, off, 64));
  __shared__ float red[8];
  if ((t & 63) == 0) red[t >> 6] = m;
  __syncthreads();
  m = fmaxf(fmaxf(red[0], red[1]), fmaxf(red[2], red[3]));

  float sum = 0.f;
#pragma unroll
  for (int i = 0; i < 8; i++) {
    int k = t + i * 256;
    float x = (k <= q) ? __expf(e[i] - m) : 0.f;
    e[i] = x;
    sum += x;
  }
#pragma unroll
  for (int off = 1; off < 64; off <<= 1) sum += __shfl_xor(sum, off, 64);
  if ((t & 63) == 0) red[4 + (t >> 6)] = sum;
  __syncthreads();
  sum = red[4] + red[5] + red[6] + red[7];
  float inv = 1.f / sum;
#pragma unroll
  for (int i = 0; i < 8; i++) {
    int k = t + i * 256;
    if (k < kend) p[k] = __float2bfloat16(e[i] * inv);
  }
}

// ---------------- bf16 transpose with strides ----------------
__global__ __launch_bounds__(256)
void k_transpose_bf16(const bf16* __restrict__ V, bf16* __restrict__ Vt,
                      int in_ld, int out_ld, long in_bs, long out_bs) {
  __shared__ bf16 tile[64][68];
  const bf16* v = V + (long)blockIdx.z * in_bs;
  bf16* vt = Vt + (long)blockIdx.z * out_bs;
  const int k0 = blockIdx.y * 64;
  const int d0 = blockIdx.x * 64;
  const int t = threadIdx.x;
  const int c4 = (t & 15) * 4;
  const int r = t >> 4;
#pragma unroll
  for (int p2 = 0; p2 < 4; p2++) {
    int row = r + p2 * 16;
    bf16x4v val = *(const bf16x4v*)&v[(long)(k0 + row) * in_ld + d0 + c4];
    *(bf16x4v*)&tile[row][c4] = val;
  }
  __syncthreads();
#pragma unroll
  for (int p2 = 0; p2 < 4; p2++) {
    int drow = r + p2 * 16;
    bf16q o{tile[c4 + 0][drow], tile[c4 + 1][drow],
            tile[c4 + 2][drow], tile[c4 + 3][drow]};
    *(bf16q*)&vt[(long)(d0 + drow) * out_ld + k0 + c4] = o;
  }
}

// ---------------- launch ----------------
extern "C" void kernel_launch(void* const* d_in, const int* in_sizes, int n_in,
                              void* d_out, int out_size, void* d_ws, size_t ws_size,
                              hipStream_t stream)
{
  const float* X  = (const float*)d_in[0];
  const float* Wq = (const float*)d_in[1];
  const float* bq = (const float*)d_in[2];
  const float* Wk = (const float*)d_in[3];
  const float* bk = (const float*)d_in[4];
  const float* Wv = (const float*)d_in[5];
  const float* bv = (const float*)d_in[6];
  const float* Wo = (const float*)d_in[7];
  const float* bo = (const float*)d_in[8];

  const long Nt = 2048, D = 1024;
  const long TOK = 4 * Nt;  // 8192

  char* ws = (char*)d_ws;
  const size_t MB = 1024 * 1024;
  bf16*  QKVb = (bf16*)(ws + 0);          // 48 MiB  [8192][3072]
  bf16*  Wcat = (bf16*)(ws + 48 * MB);    //  6 MiB  [3072][1024]
  bf16*  Wob  = (bf16*)(ws + 54 * MB);    //  2 MiB
  float* bcat = (float*)(ws + 56 * MB);   //  12 KiB [3072]
  bf16*  Vt   = (bf16*)(ws + 57 * MB);    // 16 MiB  [4][1024][2048]
  bf16*  Cx   = (bf16*)(ws + 73 * MB);    // 16 MiB
  bf16*  Pb   = (bf16*)(ws + 89 * MB);    // 32 MiB
  bf16*  Xb   = (bf16*)(ws + 121 * MB);   // 16 MiB
  float* Sf   = (float*)(ws + 121 * MB);  // 64 MiB (overlaps Xb; Xb dead after QKV)

  const int SMEM = 131072;
  hipFuncSetAttribute((const void*)k_gemm8<true,  true,  0>,
                      hipFuncAttributeMaxDynamicSharedMemorySize, SMEM);
  hipFuncSetAttribute((const void*)k_gemm8<false, false, 1>,
                      hipFuncAttributeMaxDynamicSharedMemorySize, SMEM);
  hipFuncSetAttribute((const void*)k_gemm8<true,  false, 2>,
                      hipFuncAttributeMaxDynamicSharedMemorySize, SMEM);
  hipFuncSetAttribute((const void*)k_gemm8<false, true,  0>,
                      hipFuncAttributeMaxDynamicSharedMemorySize, SMEM);

  dim3 blk(256), blk8(512);

  // converts
  k_f32_to_bf16<<<dim3(8192), blk, 0, stream>>>(X,  Xb,  TOK * D / 4);
  k_f32_to_bf16<<<dim3(1024), blk, 0, stream>>>(Wq, Wcat,             D * D / 4);
  k_f32_to_bf16<<<dim3(1024), blk, 0, stream>>>(Wk, Wcat + D * D,     D * D / 4);
  k_f32_to_bf16<<<dim3(1024), blk, 0, stream>>>(Wv, Wcat + 2 * D * D, D * D / 4);
  k_f32_to_bf16<<<dim3(1024), blk, 0, stream>>>(Wo, Wob,              D * D / 4);

  hipMemcpyAsync(bcat,       bq, D * 4, hipMemcpyDeviceToDevice, stream);
  hipMemcpyAsync(bcat + D,   bk, D * 4, hipMemcpyDeviceToDevice, stream);
  hipMemcpyAsync(bcat + 2*D, bv, D * 4, hipMemcpyDeviceToDevice, stream);

  // fused QKV: [8192,3072] = Xb @ Wcat^T + bcat
  k_gemm8<true, true, 0><<<dim3(12, 32, 1), blk8, SMEM, stream>>>(
      Xb, Wcat, bcat, QKVb, 8192, 3072, 1024, 1.f,
      1024, 1024, 3072, 0, 0, 0);

  // V transpose per batch
  k_transpose_bf16<<<dim3(16, 32, 4), blk, 0, stream>>>(
      QKVb + 2048, Vt, 3072, 2048, Nt * 3072, D * Nt);

  // S = Q @ K^T / 32 (causal tile skip, fp32)
  k_gemm8<false, false, 1><<<dim3(8, 8, 4), blk8, SMEM, stream>>>(
      QKVb, QKVb + 1024, nullptr, Sf, 2048, 2048, 1024, 0.03125f,
      3072, 3072, 2048, Nt * 3072, Nt * 3072, Nt * Nt);

  // softmax -> P bf16
  k_softmax_causal<<<dim3(8192), blk, 0, stream>>>(Sf, Pb);

  // ctx = P @ Vt^T (k-limited)
  k_gemm8<true, false, 2><<<dim3(4, 8, 4), blk8, SMEM, stream>>>(
      Pb, Vt, nullptr, Cx, 2048, 1024, 2048, 1.f,
      2048, 2048, 1024, Nt * Nt, D * Nt, Nt * D);

  // out = ctx @ Wo^T + bo (fp32)
  k_gemm8<false, true, 0><<<dim3(4, 32, 1), blk8, SMEM, stream>>>(
      Cx, Wob, bo, d_out, 8192, 1024, 1024, 1.f,
      1024, 1024, 1024, 0, 0, 0);
}

// Round 8
// 311.712 us; speedup vs baseline: 1.1473x; 1.0937x over previous
//
#include <hip/hip_runtime.h>
#include <hip/hip_bf16.h>
#include <stdint.h>

// Causal self-attention, B=4, N=2048, D=1024.
// R8 (= R7 resubmit; R6/R7 never ran — broker timeouts):
// 128^2/BK=32 GEMMs with TRI-BUFFERED counted-vmcnt pipeline
// (1 raw barrier per K-step, vmcnt(4) gate, loads span 2 K-steps),
// 2-bit XOR involution swizzle ((off>>6)&3)<<4 — uniform 8 lanes/slot,
// 48KB LDS -> 3 blk/CU. S materialized bf16 (scale fused). Vec bf16 softmax.

typedef __hip_bfloat16 bf16;
typedef short bf16x8v __attribute__((ext_vector_type(8)));
typedef short bf16x4v __attribute__((ext_vector_type(4)));
typedef float f32x4   __attribute__((ext_vector_type(4)));

#define DEV static __device__ __forceinline__

DEV void gload_lds16(const void* g, void* l) {
  __builtin_amdgcn_global_load_lds(
      (const __attribute__((address_space(1))) void*)g,
      (__attribute__((address_space(3))) void*)l, 16u, 0, 0u);
}

struct alignas(8) bf16q { bf16 a, b, c, d; };

// ---------------- f32 -> bf16 convert ----------------
__global__ __launch_bounds__(256)
void k_f32_to_bf16(const float* __restrict__ in, bf16* __restrict__ out, long n4) {
  long i = (long)blockIdx.x * blockDim.x + threadIdx.x;
  if (i >= n4) return;
  float4 v = ((const float4*)in)[i];
  bf16q o{__float2bfloat16(v.x), __float2bfloat16(v.y),
          __float2bfloat16(v.z), __float2bfloat16(v.w)};
  ((bf16q*)out)[i] = o;
}

// ---------------- 128^2 tri-buffer MFMA GEMM body ----------------
// C = A(MxK) @ B(NxK)^T [+bias], 4 waves (2x2), per-wave 64x64 = acc[4][4].
// LDS: 3 slots x (A 8KB + B 8KB) = 48KB.
// Swizzle (involution, both sides): off ^= ((off>>6)&3)<<4 — permutes the two
// 16B-chunk bits by row&3; rows (bit>=6) untouched. Read slot distribution:
// quad = (fr&1)*4 + (kq^(fr&3)) -> uniform 8 lanes per bank-quad (conflict-free).
// Pipeline: stage(0),stage(1); iter t: vmcnt(4) [last: 0] -> s_barrier ->
// stage(t+2, slot (t+2)%3) -> ds_read slot t%3 -> MFMA. No trailing barrier:
// passing the next gate implies all waves' MFMAs issued => their ds_reads done.
template<bool OUT_BF16, bool HAS_BIAS, int CAUSAL>
DEV void gemm_body(const bf16* __restrict__ A, const bf16* __restrict__ B,
                   const float* __restrict__ bias, void* __restrict__ Cout,
                   int K, float scale, int lda, int ldb, int ldc,
                   long sA, long sB, long sC)
{
  __shared__ char smem[49152];
  const int tn = blockIdx.x, tm = blockIdx.y, bz = blockIdx.z;
  if (CAUSAL == 1 && tn > tm) return;
  const bf16* Ab = A + (long)bz * sA;
  const bf16* Bb = B + (long)bz * sB;
  const int m0 = tm * 128, n0 = tn * 128;

  int kend = K;
  if (CAUSAL == 2) { int ke = (tm + 1) * 128; kend = ke < K ? ke : K; }
  const int nt = kend >> 5;   // >= 4 in all our uses

  const int t = threadIdx.x;
  const int lane = t & 63;
  const int w = t >> 6;
  const int wr = w >> 1, wc = w & 1;
  const int fr = lane & 15;
  const int kq = lane >> 4;      // 16B chunk (8 bf16) within 64B row

  // stage K-tile tt into slot: 4 loads/thread (2 A + 2 B).
  auto stage = [&](int tt, int slot) {
    char* dA = smem + slot * 8192;
    char* dB = smem + 24576 + slot * 8192;
    const int k0 = tt << 5;
#pragma unroll
    for (int j = 0; j < 2; ++j) {
      int lin16 = (t + j * 256) * 16;                 // linear LDS dest byte
      int lg = lin16 ^ (((lin16 >> 6) & 3) << 4);     // logical byte (involution)
      int row = lg >> 6;                              // 0..127
      int el = (lg & 63) >> 1;                        // 0..63, multiple of 8
      gload_lds16(Ab + (long)(m0 + row) * lda + (k0 + el), dA + lin16);
      gload_lds16(Bb + (long)(n0 + row) * ldb + (k0 + el), dB + lin16);
    }
  };

  f32x4 acc[4][4] = {};

  stage(0, 0);
  stage(1, 1);

  int cur = 0, s2 = 2;
  for (int ts = 0; ts < nt; ++ts) {
    if (ts + 1 < nt) asm volatile("s_waitcnt vmcnt(4)" ::: "memory");
    else             asm volatile("s_waitcnt vmcnt(0)" ::: "memory");
    __builtin_amdgcn_s_barrier();
    __builtin_amdgcn_sched_barrier(0);

    if (ts + 2 < nt) stage(ts + 2, s2);

    const char* As_ = smem + cur * 8192;
    const char* Bs_ = smem + 24576 + cur * 8192;
    bf16x8v af[4], bf_[4];
#pragma unroll
    for (int i = 0; i < 4; ++i) {
      int off = (wr * 64 + i * 16 + fr) * 64 + kq * 16;
      int lam = off ^ (((off >> 6) & 3) << 4);
      af[i] = *(const bf16x8v*)(As_ + lam);
    }
#pragma unroll
    for (int j = 0; j < 4; ++j) {
      int off = (wc * 64 + j * 16 + fr) * 64 + kq * 16;
      int lam = off ^ (((off >> 6) & 3) << 4);
      bf_[j] = *(const bf16x8v*)(Bs_ + lam);
    }

#pragma unroll
    for (int i = 0; i < 4; ++i)
#pragma unroll
      for (int j = 0; j < 4; ++j)
        acc[i][j] = __builtin_amdgcn_mfma_f32_16x16x32_bf16(af[i], bf_[j], acc[i][j], 0, 0, 0);

    cur = (cur == 2) ? 0 : cur + 1;
    s2  = (s2 == 2) ? 0 : s2 + 1;
  }

  // epilogue: C/D layout col = lane&15, row = (lane>>4)*4 + reg
  const int rq = (lane >> 4) * 4;
#pragma unroll
  for (int i = 0; i < 4; ++i) {
#pragma unroll
    for (int j = 0; j < 4; ++j) {
      const int n = n0 + wc * 64 + j * 16 + fr;
      const float bv_ = HAS_BIAS ? bias[n] : 0.f;
#pragma unroll
      for (int r = 0; r < 4; ++r) {
        const int m = m0 + wr * 64 + i * 16 + rq + r;
        float v = acc[i][j][r] * scale + bv_;
        if (OUT_BF16)
          ((bf16*)Cout + (long)bz * sC)[(long)m * ldc + n] = __float2bfloat16(v);
        else
          ((float*)Cout + (long)bz * sC)[(long)m * ldc + n] = v;
      }
    }
  }
}

// distinct names per stage for profiling
__global__ __launch_bounds__(256, 3)
void k_qkv(const bf16* A, const bf16* B, const float* bias, void* C,
           int K, float scale, int lda, int ldb, int ldc) {
  gemm_body<true, true, 0>(A, B, bias, C, K, scale, lda, ldb, ldc, 0, 0, 0);
}
__global__ __launch_bounds__(256, 3)
void k_sgemm(const bf16* A, const bf16* B, void* C,
             int K, float scale, int lda, int ldb, int ldc,
             long sA, long sB, long sC) {
  gemm_body<true, false, 1>(A, B, nullptr, C, K, scale, lda, ldb, ldc, sA, sB, sC);
}
__global__ __launch_bounds__(256, 3)
void k_pv(const bf16* A, const bf16* B, void* C,
          int K, float scale, int lda, int ldb, int ldc,
          long sA, long sB, long sC) {
  gemm_body<true, false, 2>(A, B, nullptr, C, K, scale, lda, ldb, ldc, sA, sB, sC);
}
__global__ __launch_bounds__(256, 3)
void k_oproj(const bf16* A, const bf16* B, const float* bias, void* C,
             int K, float scale, int lda, int ldb, int ldc) {
  gemm_body<false, true, 0>(A, B, bias, C, K, scale, lda, ldb, ldc, 0, 0, 0);
}

// ---------------- causal row softmax: S bf16 -> P bf16 (vectorized) ----------
// one block (256 thr) per row; thread t owns k in [8t, 8t+8).
__global__ __launch_bounds__(256)
void k_softmax(const bf16* __restrict__ S, bf16* __restrict__ P) {
  const long row = blockIdx.x;
  const int q = (int)(row & 2047);
  const int kend = ((q >> 7) + 1) << 7;   // 128-aligned (matches PV k-limit)
  const bf16* s = S + row * 2048;
  bf16* p = P + row * 2048;
  const int t = threadIdx.x;

  bf16x8v v = *(const bf16x8v*)&s[t * 8];
  float e[8];
  float m = -3.4e38f;
#pragma unroll
  for (int i = 0; i < 8; i++) {
    int k = t * 8 + i;
    unsigned short u = (unsigned short)v[i];
    float x = (k <= q) ? __bfloat162float(*(const bf16*)&u) : -3.4e38f;
    e[i] = x;
    m = fmaxf(m, x);
  }
#pragma unroll
  for (int off = 1; off < 64; off <<= 1) m = fmaxf(m, __shfl_xor(m, off, 64));
  __shared__ float red[8];
  if ((t & 63) == 0) red[t >> 6] = m;
  __syncthreads();
  m = fmaxf(fmaxf(red[0], red[1]), fmaxf(red[2], red[3]));

  float sum = 0.f;
#pragma unroll
  for (int i = 0; i < 8; i++) {
    int k = t * 8 + i;
    float x = (k <= q) ? __expf(e[i] - m) : 0.f;
    e[i] = x;
    sum += x;
  }
#pragma unroll
  for (int off = 1; off < 64; off <<= 1) sum += __shfl_xor(sum, off, 64);
  if ((t & 63) == 0) red[4 + (t >> 6)] = sum;
  __syncthreads();
  sum = red[4] + red[5] + red[6] + red[7];
  const float inv = 1.f / sum;

  if (t * 8 < kend) {
    bf16x8v o;
#pragma unroll
    for (int i = 0; i < 8; i++) {
      bf16 b = __float2bfloat16(e[i] * inv);
      o[i] = *(const short*)&b;
    }
    *(bf16x8v*)&p[t * 8] = o;
  }
}

// ---------------- bf16 transpose with strides ----------------
__global__ __launch_bounds__(256)
void k_transpose_bf16(const bf16* __restrict__ V, bf16* __restrict__ Vt,
                      int in_ld, int out_ld, long in_bs, long out_bs) {
  __shared__ bf16 tile[64][68];
  const bf16* v = V + (long)blockIdx.z * in_bs;
  bf16* vt = Vt + (long)blockIdx.z * out_bs;
  const int k0 = blockIdx.y * 64;
  const int d0 = blockIdx.x * 64;
  const int t = threadIdx.x;
  const int c4 = (t & 15) * 4;
  const int r = t >> 4;
#pragma unroll
  for (int p2 = 0; p2 < 4; p2++) {
    int row = r + p2 * 16;
    bf16x4v val = *(const bf16x4v*)&v[(long)(k0 + row) * in_ld + d0 + c4];
    *(bf16x4v*)&tile[row][c4] = val;
  }
  __syncthreads();
#pragma unroll
  for (int p2 = 0; p2 < 4; p2++) {
    int drow = r + p2 * 16;
    bf16q o{tile[c4 + 0][drow], tile[c4 + 1][drow],
            tile[c4 + 2][drow], tile[c4 + 3][drow]};
    *(bf16q*)&vt[(long)(d0 + drow) * out_ld + k0 + c4] = o;
  }
}

// ---------------- launch ----------------
extern "C" void kernel_launch(void* const* d_in, const int* in_sizes, int n_in,
                              void* d_out, int out_size, void* d_ws, size_t ws_size,
                              hipStream_t stream)
{
  const float* X  = (const float*)d_in[0];
  const float* Wq = (const float*)d_in[1];
  const float* bq = (const float*)d_in[2];
  const float* Wk = (const float*)d_in[3];
  const float* bk = (const float*)d_in[4];
  const float* Wv = (const float*)d_in[5];
  const float* bv = (const float*)d_in[6];
  const float* Wo = (const float*)d_in[7];
  const float* bo = (const float*)d_in[8];

  const long Nt = 2048, D = 1024;
  const long TOK = 4 * Nt;  // 8192

  char* ws = (char*)d_ws;
  const size_t MB = 1024 * 1024;
  bf16*  QKVb = (bf16*)(ws + 0);          // 48 MiB  [8192][3072]
  bf16*  Wcat = (bf16*)(ws + 48 * MB);    //  6 MiB  [3072][1024]
  bf16*  Wob  = (bf16*)(ws + 54 * MB);    //  2 MiB
  float* bcat = (float*)(ws + 56 * MB);   //  12 KiB [3072]
  bf16*  Vt   = (bf16*)(ws + 57 * MB);    // 16 MiB  [4][1024][2048]
  bf16*  Cx   = (bf16*)(ws + 73 * MB);    // 16 MiB
  bf16*  Pb   = (bf16*)(ws + 89 * MB);    // 32 MiB
  bf16*  Xb   = (bf16*)(ws + 121 * MB);   // 16 MiB
  bf16*  Sb   = (bf16*)(ws + 137 * MB);   // 32 MiB  [4][2048][2048] bf16

  dim3 blk(256);

  // converts
  k_f32_to_bf16<<<dim3(8192), blk, 0, stream>>>(X,  Xb,  TOK * D / 4);
  k_f32_to_bf16<<<dim3(1024), blk, 0, stream>>>(Wq, Wcat,             D * D / 4);
  k_f32_to_bf16<<<dim3(1024), blk, 0, stream>>>(Wk, Wcat + D * D,     D * D / 4);
  k_f32_to_bf16<<<dim3(1024), blk, 0, stream>>>(Wv, Wcat + 2 * D * D, D * D / 4);
  k_f32_to_bf16<<<dim3(1024), blk, 0, stream>>>(Wo, Wob,              D * D / 4);

  hipMemcpyAsync(bcat,       bq, D * 4, hipMemcpyDeviceToDevice, stream);
  hipMemcpyAsync(bcat + D,   bk, D * 4, hipMemcpyDeviceToDevice, stream);
  hipMemcpyAsync(bcat + 2*D, bv, D * 4, hipMemcpyDeviceToDevice, stream);

  // fused QKV: [8192,3072] = Xb @ Wcat^T + bcat
  k_qkv<<<dim3(24, 64, 1), blk, 0, stream>>>(
      Xb, Wcat, bcat, QKVb, 1024, 1.f, 1024, 1024, 3072);

  // V transpose per batch: Vt[b][d][k]
  k_transpose_bf16<<<dim3(16, 32, 4), blk, 0, stream>>>(
      QKVb + 2048, Vt, 3072, 2048, Nt * 3072, D * Nt);

  // S = Q @ K^T / 32 (causal tile skip, bf16 out)
  k_sgemm<<<dim3(16, 16, 4), blk, 0, stream>>>(
      QKVb, QKVb + 1024, Sb, 1024, 0.03125f,
      3072, 3072, 2048, Nt * 3072, Nt * 3072, Nt * Nt);

  // softmax -> P bf16 (causal-trimmed, vectorized)
  k_softmax<<<dim3(8192), blk, 0, stream>>>(Sb, Pb);

  // ctx = P @ Vt^T (k limited per 128-q-tile)
  k_pv<<<dim3(8, 16, 4), blk, 0, stream>>>(
      Pb, Vt, Cx, 2048, 1.f, 2048, 2048, 1024,
      Nt * Nt, D * Nt, Nt * D);

  // out = ctx @ Wo^T + bo (fp32)
  k_oproj<<<dim3(8, 64, 1), blk, 0, stream>>>(
      Cx, Wob, bo, d_out, 1024, 1.f, 1024, 1024, 1024);
}

// Round 11
// 311.424 us; speedup vs baseline: 1.1484x; 1.0009x over previous
//
#include <hip/hip_runtime.h>
#include <hip/hip_bf16.h>
#include <stdint.h>

// Causal self-attention, B=4, N=2048, D=1024.
// R11 (= R9 resubmit; R9/R10 never ran — broker timeouts).
// R9 = R8 with the LDS swizzle re-keyed: off ^= ((off>>7)&3)<<4 (row bits 1-2),
// giving uniform 2 lanes/bank-quad per 16-lane service group (R8's fr&3 keying
// left 4x4 clustering -> 6.29M conflicts, identical to unswizzled).
// Structure: 128^2/BK=32 GEMMs, tri-buffered counted-vmcnt pipeline
// (1 barrier per K-step, vmcnt(4) gate), 48KB LDS -> 3 blk/CU.
// S materialized bf16 (scale fused). Vec bf16 softmax.

typedef __hip_bfloat16 bf16;
typedef short bf16x8v __attribute__((ext_vector_type(8)));
typedef short bf16x4v __attribute__((ext_vector_type(4)));
typedef float f32x4   __attribute__((ext_vector_type(4)));

#define DEV static __device__ __forceinline__

DEV void gload_lds16(const void* g, void* l) {
  __builtin_amdgcn_global_load_lds(
      (const __attribute__((address_space(1))) void*)g,
      (__attribute__((address_space(3))) void*)l, 16u, 0, 0u);
}

struct alignas(8) bf16q { bf16 a, b, c, d; };

// ---------------- f32 -> bf16 convert ----------------
__global__ __launch_bounds__(256)
void k_f32_to_bf16(const float* __restrict__ in, bf16* __restrict__ out, long n4) {
  long i = (long)blockIdx.x * blockDim.x + threadIdx.x;
  if (i >= n4) return;
  float4 v = ((const float4*)in)[i];
  bf16q o{__float2bfloat16(v.x), __float2bfloat16(v.y),
          __float2bfloat16(v.z), __float2bfloat16(v.w)};
  ((bf16q*)out)[i] = o;
}

// ---------------- 128^2 tri-buffer MFMA GEMM body ----------------
// C = A(MxK) @ B(NxK)^T [+bias], 4 waves (2x2), per-wave 64x64 = acc[4][4].
// LDS: 3 slots x (A 8KB + B 8KB) = 48KB.
// Swizzle (involution, both sides): off ^= ((off>>7)&3)<<4 — chunk bits 4-5
// XOR'd with ROW bits 1-2 (off bits 7-8, untouched by the XOR).
// Read slot {bit6,bit5,bit4} = {fr&1, kq^((fr>>1)&3)}: per 16-lane service
// group each 16B slot gets exactly 2 lanes (HW floor) -> conflict-free.
// Pipeline: stage(0),stage(1); iter t: vmcnt(4) [last: 0] -> s_barrier ->
// stage(t+2, slot (t+2)%3) -> ds_read slot t%3 -> MFMA. No trailing barrier:
// passing the next gate implies all waves' MFMAs issued => their ds_reads done.
template<bool OUT_BF16, bool HAS_BIAS, int CAUSAL>
DEV void gemm_body(const bf16* __restrict__ A, const bf16* __restrict__ B,
                   const float* __restrict__ bias, void* __restrict__ Cout,
                   int K, float scale, int lda, int ldb, int ldc,
                   long sA, long sB, long sC)
{
  __shared__ char smem[49152];
  const int tn = blockIdx.x, tm = blockIdx.y, bz = blockIdx.z;
  if (CAUSAL == 1 && tn > tm) return;
  const bf16* Ab = A + (long)bz * sA;
  const bf16* Bb = B + (long)bz * sB;
  const int m0 = tm * 128, n0 = tn * 128;

  int kend = K;
  if (CAUSAL == 2) { int ke = (tm + 1) * 128; kend = ke < K ? ke : K; }
  const int nt = kend >> 5;   // >= 4 in all our uses

  const int t = threadIdx.x;
  const int lane = t & 63;
  const int w = t >> 6;
  const int wr = w >> 1, wc = w & 1;
  const int fr = lane & 15;
  const int kq = lane >> 4;      // 16B chunk (8 bf16) within 64B row

  // stage K-tile tt into slot: 4 loads/thread (2 A + 2 B).
  auto stage = [&](int tt, int slot) {
    char* dA = smem + slot * 8192;
    char* dB = smem + 24576 + slot * 8192;
    const int k0 = tt << 5;
#pragma unroll
    for (int j = 0; j < 2; ++j) {
      int lin16 = (t + j * 256) * 16;                 // linear LDS dest byte
      int lg = lin16 ^ (((lin16 >> 7) & 3) << 4);     // logical byte (involution)
      int row = lg >> 6;                              // 0..127
      int el = (lg & 63) >> 1;                        // 0..63, multiple of 8
      gload_lds16(Ab + (long)(m0 + row) * lda + (k0 + el), dA + lin16);
      gload_lds16(Bb + (long)(n0 + row) * ldb + (k0 + el), dB + lin16);
    }
  };

  f32x4 acc[4][4] = {};

  stage(0, 0);
  stage(1, 1);

  int cur = 0, s2 = 2;
  for (int ts = 0; ts < nt; ++ts) {
    if (ts + 1 < nt) asm volatile("s_waitcnt vmcnt(4)" ::: "memory");
    else             asm volatile("s_waitcnt vmcnt(0)" ::: "memory");
    __builtin_amdgcn_s_barrier();
    __builtin_amdgcn_sched_barrier(0);

    if (ts + 2 < nt) stage(ts + 2, s2);

    const char* As_ = smem + cur * 8192;
    const char* Bs_ = smem + 24576 + cur * 8192;
    bf16x8v af[4], bf_[4];
#pragma unroll
    for (int i = 0; i < 4; ++i) {
      int off = (wr * 64 + i * 16 + fr) * 64 + kq * 16;
      int lam = off ^ (((off >> 7) & 3) << 4);
      af[i] = *(const bf16x8v*)(As_ + lam);
    }
#pragma unroll
    for (int j = 0; j < 4; ++j) {
      int off = (wc * 64 + j * 16 + fr) * 64 + kq * 16;
      int lam = off ^ (((off >> 7) & 3) << 4);
      bf_[j] = *(const bf16x8v*)(Bs_ + lam);
    }

#pragma unroll
    for (int i = 0; i < 4; ++i)
#pragma unroll
      for (int j = 0; j < 4; ++j)
        acc[i][j] = __builtin_amdgcn_mfma_f32_16x16x32_bf16(af[i], bf_[j], acc[i][j], 0, 0, 0);

    cur = (cur == 2) ? 0 : cur + 1;
    s2  = (s2 == 2) ? 0 : s2 + 1;
  }

  // epilogue: C/D layout col = lane&15, row = (lane>>4)*4 + reg
  const int rq = (lane >> 4) * 4;
#pragma unroll
  for (int i = 0; i < 4; ++i) {
#pragma unroll
    for (int j = 0; j < 4; ++j) {
      const int n = n0 + wc * 64 + j * 16 + fr;
      const float bv_ = HAS_BIAS ? bias[n] : 0.f;
#pragma unroll
      for (int r = 0; r < 4; ++r) {
        const int m = m0 + wr * 64 + i * 16 + rq + r;
        float v = acc[i][j][r] * scale + bv_;
        if (OUT_BF16)
          ((bf16*)Cout + (long)bz * sC)[(long)m * ldc + n] = __float2bfloat16(v);
        else
          ((float*)Cout + (long)bz * sC)[(long)m * ldc + n] = v;
      }
    }
  }
}

// distinct names per stage for profiling
__global__ __launch_bounds__(256, 3)
void k_qkv(const bf16* A, const bf16* B, const float* bias, void* C,
           int K, float scale, int lda, int ldb, int ldc) {
  gemm_body<true, true, 0>(A, B, bias, C, K, scale, lda, ldb, ldc, 0, 0, 0);
}
__global__ __launch_bounds__(256, 3)
void k_sgemm(const bf16* A, const bf16* B, void* C,
             int K, float scale, int lda, int ldb, int ldc,
             long sA, long sB, long sC) {
  gemm_body<true, false, 1>(A, B, nullptr, C, K, scale, lda, ldb, ldc, sA, sB, sC);
}
__global__ __launch_bounds__(256, 3)
void k_pv(const bf16* A, const bf16* B, void* C,
          int K, float scale, int lda, int ldb, int ldc,
          long sA, long sB, long sC) {
  gemm_body<true, false, 2>(A, B, nullptr, C, K, scale, lda, ldb, ldc, sA, sB, sC);
}
__global__ __launch_bounds__(256, 3)
void k_oproj(const bf16* A, const bf16* B, const float* bias, void* C,
             int K, float scale, int lda, int ldb, int ldc) {
  gemm_body<false, true, 0>(A, B, bias, C, K, scale, lda, ldb, ldc, 0, 0, 0);
}

// ---------------- causal row softmax: S bf16 -> P bf16 (vectorized) ----------
// one block (256 thr) per row; thread t owns k in [8t, 8t+8).
__global__ __launch_bounds__(256)
void k_softmax(const bf16* __restrict__ S, bf16* __restrict__ P) {
  const long row = blockIdx.x;
  const int q = (int)(row & 2047);
  const int kend = ((q >> 7) + 1) << 7;   // 128-aligned (matches PV k-limit)
  const bf16* s = S + row * 2048;
  bf16* p = P + row * 2048;
  const int t = threadIdx.x;

  bf16x8v v = *(const bf16x8v*)&s[t * 8];
  float e[8];
  float m = -3.4e38f;
#pragma unroll
  for (int i = 0; i < 8; i++) {
    int k = t * 8 + i;
    unsigned short u = (unsigned short)v[i];
    float x = (k <= q) ? __bfloat162float(*(const bf16*)&u) : -3.4e38f;
    e[i] = x;
    m = fmaxf(m, x);
  }
#pragma unroll
  for (int off = 1; off < 64; off <<= 1) m = fmaxf(m, __shfl_xor(m, off, 64));
  __shared__ float red[8];
  if ((t & 63) == 0) red[t >> 6] = m;
  __syncthreads();
  m = fmaxf(fmaxf(red[0], red[1]), fmaxf(red[2], red[3]));

  float sum = 0.f;
#pragma unroll
  for (int i = 0; i < 8; i++) {
    int k = t * 8 + i;
    float x = (k <= q) ? __expf(e[i] - m) : 0.f;
    e[i] = x;
    sum += x;
  }
#pragma unroll
  for (int off = 1; off < 64; off <<= 1) sum += __shfl_xor(sum, off, 64);
  if ((t & 63) == 0) red[4 + (t >> 6)] = sum;
  __syncthreads();
  sum = red[4] + red[5] + red[6] + red[7];
  const float inv = 1.f / sum;

  if (t * 8 < kend) {
    bf16x8v o;
#pragma unroll
    for (int i = 0; i < 8; i++) {
      bf16 b = __float2bfloat16(e[i] * inv);
      o[i] = *(const short*)&b;
    }
    *(bf16x8v*)&p[t * 8] = o;
  }
}

// ---------------- bf16 transpose with strides ----------------
__global__ __launch_bounds__(256)
void k_transpose_bf16(const bf16* __restrict__ V, bf16* __restrict__ Vt,
                      int in_ld, int out_ld, long in_bs, long out_bs) {
  __shared__ bf16 tile[64][68];
  const bf16* v = V + (long)blockIdx.z * in_bs;
  bf16* vt = Vt + (long)blockIdx.z * out_bs;
  const int k0 = blockIdx.y * 64;
  const int d0 = blockIdx.x * 64;
  const int t = threadIdx.x;
  const int c4 = (t & 15) * 4;
  const int r = t >> 4;
#pragma unroll
  for (int p2 = 0; p2 < 4; p2++) {
    int row = r + p2 * 16;
    bf16x4v val = *(const bf16x4v*)&v[(long)(k0 + row) * in_ld + d0 + c4];
    *(bf16x4v*)&tile[row][c4] = val;
  }
  __syncthreads();
#pragma unroll
  for (int p2 = 0; p2 < 4; p2++) {
    int drow = r + p2 * 16;
    bf16q o{tile[c4 + 0][drow], tile[c4 + 1][drow],
            tile[c4 + 2][drow], tile[c4 + 3][drow]};
    *(bf16q*)&vt[(long)(d0 + drow) * out_ld + k0 + c4] = o;
  }
}

// ---------------- launch ----------------
extern "C" void kernel_launch(void* const* d_in, const int* in_sizes, int n_in,
                              void* d_out, int out_size, void* d_ws, size_t ws_size,
                              hipStream_t stream)
{
  const float* X  = (const float*)d_in[0];
  const float* Wq = (const float*)d_in[1];
  const float* bq = (const float*)d_in[2];
  const float* Wk = (const float*)d_in[3];
  const float* bk = (const float*)d_in[4];
  const float* Wv = (const float*)d_in[5];
  const float* bv = (const float*)d_in[6];
  const float* Wo = (const float*)d_in[7];
  const float* bo = (const float*)d_in[8];

  const long Nt = 2048, D = 1024;
  const long TOK = 4 * Nt;  // 8192

  char* ws = (char*)d_ws;
  const size_t MB = 1024 * 1024;
  bf16*  QKVb = (bf16*)(ws + 0);          // 48 MiB  [8192][3072]
  bf16*  Wcat = (bf16*)(ws + 48 * MB);    //  6 MiB  [3072][1024]
  bf16*  Wob  = (bf16*)(ws + 54 * MB);    //  2 MiB
  float* bcat = (float*)(ws + 56 * MB);   //  12 KiB [3072]
  bf16*  Vt   = (bf16*)(ws + 57 * MB);    // 16 MiB  [4][1024][2048]
  bf16*  Cx   = (bf16*)(ws + 73 * MB);    // 16 MiB
  bf16*  Pb   = (bf16*)(ws + 89 * MB);    // 32 MiB
  bf16*  Xb   = (bf16*)(ws + 121 * MB);   // 16 MiB
  bf16*  Sb   = (bf16*)(ws + 137 * MB);   // 32 MiB  [4][2048][2048] bf16

  dim3 blk(256);

  // converts
  k_f32_to_bf16<<<dim3(8192), blk, 0, stream>>>(X,  Xb,  TOK * D / 4);
  k_f32_to_bf16<<<dim3(1024), blk, 0, stream>>>(Wq, Wcat,             D * D / 4);
  k_f32_to_bf16<<<dim3(1024), blk, 0, stream>>>(Wk, Wcat + D * D,     D * D / 4);
  k_f32_to_bf16<<<dim3(1024), blk, 0, stream>>>(Wv, Wcat + 2 * D * D, D * D / 4);
  k_f32_to_bf16<<<dim3(1024), blk, 0, stream>>>(Wo, Wob,              D * D / 4);

  hipMemcpyAsync(bcat,       bq, D * 4, hipMemcpyDeviceToDevice, stream);
  hipMemcpyAsync(bcat + D,   bk, D * 4, hipMemcpyDeviceToDevice, stream);
  hipMemcpyAsync(bcat + 2*D, bv, D * 4, hipMemcpyDeviceToDevice, stream);

  // fused QKV: [8192,3072] = Xb @ Wcat^T + bcat
  k_qkv<<<dim3(24, 64, 1), blk, 0, stream>>>(
      Xb, Wcat, bcat, QKVb, 1024, 1.f, 1024, 1024, 3072);

  // V transpose per batch: Vt[b][d][k]
  k_transpose_bf16<<<dim3(16, 32, 4), blk, 0, stream>>>(
      QKVb + 2048, Vt, 3072, 2048, Nt * 3072, D * Nt);

  // S = Q @ K^T / 32 (causal tile skip, bf16 out)
  k_sgemm<<<dim3(16, 16, 4), blk, 0, stream>>>(
      QKVb, QKVb + 1024, Sb, 1024, 0.03125f,
      3072, 3072, 2048, Nt * 3072, Nt * 3072, Nt * Nt);

  // softmax -> P bf16 (causal-trimmed, vectorized)
  k_softmax<<<dim3(8192), blk, 0, stream>>>(Sb, Pb);

  // ctx = P @ Vt^T (k limited per 128-q-tile)
  k_pv<<<dim3(8, 16, 4), blk, 0, stream>>>(
      Pb, Vt, Cx, 2048, 1.f, 2048, 2048, 1024,
      Nt * Nt, D * Nt, Nt * D);

  // out = ctx @ Wo^T + bo (fp32)
  k_oproj<<<dim3(8, 64, 1), blk, 0, stream>>>(
      Cx, Wob, bo, d_out, 1024, 1.f, 1024, 1024, 1024);
}